// Round 15
// baseline (105.004 us; speedup 1.0000x reference)
//
#include <hip/hip_runtime.h>
#include <hip/hip_bf16.h>

typedef __bf16 bf16;
typedef __bf16 bf16x8 __attribute__((ext_vector_type(8)));
typedef __bf16 bf16x4 __attribute__((ext_vector_type(4)));
typedef float  f32x4  __attribute__((ext_vector_type(4)));

#define B_  4
#define N_  2048
#define D_  256
#define H_  8
#define DH_ 32
#define QKV_ELEMS (B_*H_*N_*DH_)          // 2,097,152 elems = 4 MB bf16 each

#define QSC    (0.17677669529663687f * 1.4426950408889634f)
#define NBIAS  (-17.312340490667562f)

#if __has_builtin(__builtin_amdgcn_exp2f)
__device__ inline float exp2_hw(float x) { return __builtin_amdgcn_exp2f(x); }
#else
__device__ inline float exp2_hw(float x) {
    float r; asm volatile("v_exp_f32 %0, %1" : "=v"(r) : "v"(x)); return r;
}
#endif

// Async global->LDS DMA, 16 B/lane. LDS base is wave-uniform; HW adds lane*16.
__device__ inline void gload_lds16(const bf16* g, bf16* l) {
    __builtin_amdgcn_global_load_lds(
        (const __attribute__((address_space(1))) void*)g,
        (__attribute__((address_space(3))) void*)l, 16, 0, 0);
}

// s_waitcnt vmcnt(8): simm = vm[3:0]=8 | exp(7)<<4 | lgkm(15)<<8 | vm[5:4]<<14
#define WAITCNT_VM8 0x0F78

__device__ inline bf16x8 ldcvt8(const float* __restrict__ p) {
    f32x4 a = *(const f32x4*)p;
    f32x4 b = *(const f32x4*)(p + 4);
    bf16x8 r;
    r[0] = (bf16)a[0]; r[1] = (bf16)a[1]; r[2] = (bf16)a[2]; r[3] = (bf16)a[3];
    r[4] = (bf16)b[0]; r[5] = (bf16)b[1]; r[6] = (bf16)b[2]; r[7] = (bf16)b[3];
    return r;
}

// ---------------------------------------------------------------------------
// Kernel A: QKV projection (unchanged; ~8 us).
// ---------------------------------------------------------------------------
__global__ __launch_bounds__(256, 4) void qkv_proj_kernel(
    const float* __restrict__ x,
    const float* __restrict__ Wq, const float* __restrict__ bq,
    const float* __restrict__ Wk, const float* __restrict__ bk,
    const float* __restrict__ Wv, const float* __restrict__ bv,
    bf16* __restrict__ Qg, bf16* __restrict__ Kg, bf16* __restrict__ Vg)
{
    const int bh = blockIdx.x & 31, nt = blockIdx.x >> 5;
    const int h  = bh & (H_-1),    b  = bh >> 3;
    const int wave = threadIdx.x >> 6, lane = threadIdx.x & 63;
    const int l16 = lane & 15, q4 = lane >> 4;
    const int n0 = nt*64 + wave*16;

    bf16x8 wqf[2], wkf[2], wvf[2];
    f32x4  bq4[2], bk4[2];
    float  bvs[2];
    #pragma unroll
    for (int half = 0; half < 2; ++half) {
        wqf[half] = ldcvt8(Wq + (h*DH_ + half*16 + l16)*DH_ + q4*8);
        wkf[half] = ldcvt8(Wk + (h*DH_ + half*16 + l16)*DH_ + q4*8);
        wvf[half] = ldcvt8(Wv + (h*DH_ + half*16 + l16)*DH_ + q4*8);
        bq4[half] = *(const f32x4*)(bq + h*DH_ + half*16 + q4*4);
        bk4[half] = *(const f32x4*)(bk + h*DH_ + half*16 + q4*4);
        bvs[half] = bv[h*DH_ + half*16 + l16];
    }

    bf16x8 xf = ldcvt8(x + ((size_t)(b*N_ + n0 + l16))*D_ + h*DH_ + q4*8);
    const f32x4 z = {0.f,0.f,0.f,0.f};

    #pragma unroll
    for (int half = 0; half < 2; ++half) {
        f32x4 dq = __builtin_amdgcn_mfma_f32_16x16x32_bf16(wqf[half], xf, z, 0, 0, 0);
        f32x4 dk = __builtin_amdgcn_mfma_f32_16x16x32_bf16(wkf[half], xf, z, 0, 0, 0);
        f32x4 dv = __builtin_amdgcn_mfma_f32_16x16x32_bf16(xf, wvf[half], z, 0, 0, 0);
        bf16x4 pq, pk, pv;
        #pragma unroll
        for (int r = 0; r < 4; ++r) {
            pq[r] = (bf16)((dq[r] + bq4[half][r]) * QSC);
            pk[r] = (bf16)(dk[r] + bk4[half][r]);
            pv[r] = (bf16)(dv[r] + bvs[half]);
        }
        const size_t row = ((size_t)bh*N_ + n0 + l16)*DH_ + half*16 + q4*4;
        *(bf16x4*)(Qg + row) = pq;
        *(bf16x4*)(Kg + row) = pk;
        const int e = half*16 + l16;
        const size_t idx = ((size_t)bh << 16) + ((size_t)(n0 >> 5) << 10)
                         + (e << 5) + (q4 << 3) + (((n0 >> 4) & 1) << 2);
        *(bf16x4*)(Vg + idx) = pv;
    }
}

// ---------------------------------------------------------------------------
// Kernel B: flash attention, BARRIER-FREE K-loop (wave-private pipeline).
// Block = (b,h,128-row q-tile), 4 waves x 32 q-rows; grid 512, bh-minor.
// Each wave owns a private LDS double-buffer (4 KB K + 4 KB V per 64-key
// tile; 64 KB/block total -> 2 blocks/CU) and its own DMA stream:
//   iter i: issue 8 global_load_lds for tile i+1 into buf^1,
//           s_waitcnt vmcnt(8)  (tile i arrived; i+1 keeps flying),
//           compute tile i.
// No __syncthreads in the loop -> no intra-block convoy: waves start at
// staggered key offsets (softmax is key-order invariant) and free-run,
// spreading LDS/trans/MFMA pipe pressure in time. This is the AITER-style
// "never vmcnt(0)" pipeline the 2-barrier structure cannot express.
// Cost: 4x DMA redundancy (each wave loads whole tiles) - L2-resident.
// ---------------------------------------------------------------------------
__global__ __launch_bounds__(256, 2) void attn_kernel(
    const bf16* __restrict__ Qg, const bf16* __restrict__ Kg,
    const bf16* __restrict__ Vg, float* __restrict__ out)
{
    const int bh = blockIdx.x & 31;          // bh-minor: XCD-local K/V
    const int qt = blockIdx.x >> 5;
    const int h  = bh & (H_-1), b = bh >> 3;
    const int lane = threadIdx.x & 63;
    const int wave = threadIdx.x >> 6;
    const int l16 = lane & 15, q4 = lane >> 4;

    // per-wave: [buf][0..2047]=K tile, [2048..4095]=V tile (64 keys)
    __shared__ bf16 L[4][2][4096];           // 64 KB

    const bf16* Kb = Kg + (size_t)bh*N_*DH_;
    const bf16* Vb = Vg + ((size_t)bh << 16);
    const int qrow0 = qt*128 + wave*32;

    bf16x8 qb0 = *(const bf16x8*)(Qg + ((size_t)bh*N_ + qrow0 + l16)*DH_ + q4*8);
    bf16x8 qb1 = *(const bf16x8*)(Qg + ((size_t)bh*N_ + qrow0 + 16 + l16)*DH_ + q4*8);

    bf16x8 ones;
    #pragma unroll
    for (int j = 0; j < 8; ++j) ones[j] = (bf16)1.0f;

    f32x4 ot[2][2];                          // [dh-half][q-half]
    ot[0][0] = (f32x4){0,0,0,0}; ot[0][1] = (f32x4){0,0,0,0};
    ot[1][0] = (f32x4){0,0,0,0}; ot[1][1] = (f32x4){0,0,0,0};
    f32x4 osum0 = {0,0,0,0}, osum1 = {0,0,0,0};
    const f32x4 zb = {NBIAS, NBIAS, NBIAS, NBIAS};

    // per-wave phase stagger over the 32 64-key tiles (order-invariant)
    const int start = ((qt*5 + bh)*4 + wave) & 31;

    // ---- prologue: DMA tile `start` into buf 0 (8 x 1KB)
    {
        const bf16* gk = Kb + (size_t)start*2048;
        const bf16* gv = Vb + (size_t)start*2048;
        #pragma unroll
        for (int j = 0; j < 4; ++j) {
            gload_lds16(gk + j*512 + lane*8, &L[wave][0][j*512]);
            gload_lds16(gv + j*512 + lane*8, &L[wave][0][2048 + j*512]);
        }
    }

    for (int i = 0; i < 32; ++i) {
        const int cur = i & 1, nxt = cur ^ 1;
        const int tn = (start + i + 1) & 31;

        // ---- issue next tile's DMA into the other buffer (8 ops in flight)
        {
            const bf16* gk = Kb + (size_t)tn*2048;
            const bf16* gv = Vb + (size_t)tn*2048;
            #pragma unroll
            for (int j = 0; j < 4; ++j) {
                gload_lds16(gk + j*512 + lane*8, &L[wave][nxt][j*512]);
                gload_lds16(gv + j*512 + lane*8, &L[wave][nxt][2048 + j*512]);
            }
        }

        // ---- wait for THIS tile only (8 newest stay outstanding)
        __builtin_amdgcn_s_waitcnt(WAITCNT_VM8);

        const bf16* Kc = &L[wave][cur][0];
        const bf16* Vc = &L[wave][cur][2048];

        // ---- S^T (+NBIAS): 4 key-chunks x 2 q-halves
        f32x4 st[4][2];
        #pragma unroll
        for (int kc = 0; kc < 4; ++kc) {
            bf16x8 kf = *(const bf16x8*)(Kc + (kc*16 + l16)*DH_ + q4*8);
            st[kc][0] = __builtin_amdgcn_mfma_f32_16x16x32_bf16(kf, qb0, zb, 0, 0, 0);
            st[kc][1] = __builtin_amdgcn_mfma_f32_16x16x32_bf16(kf, qb1, zb, 0, 0, 0);
        }

        // ---- exp -> PV B-operand; PV + rowsum MFMAs per 32-key group
        #pragma unroll
        for (int kk = 0; kk < 2; ++kk) {
            bf16x8 pb0, pb1;
            #pragma unroll
            for (int hf = 0; hf < 2; ++hf)
                #pragma unroll
                for (int r = 0; r < 4; ++r) {
                    pb0[hf*4 + r] = (bf16)exp2_hw(st[kk*2 + hf][0][r]);
                    pb1[hf*4 + r] = (bf16)exp2_hw(st[kk*2 + hf][1][r]);
                }
            bf16x8 v0 = *(const bf16x8*)(Vc + kk*1024 + l16*DH_ + q4*8);
            bf16x8 v1 = *(const bf16x8*)(Vc + kk*1024 + (16 + l16)*DH_ + q4*8);
            ot[0][0] = __builtin_amdgcn_mfma_f32_16x16x32_bf16(v0, pb0, ot[0][0], 0, 0, 0);
            ot[1][0] = __builtin_amdgcn_mfma_f32_16x16x32_bf16(v1, pb0, ot[1][0], 0, 0, 0);
            ot[0][1] = __builtin_amdgcn_mfma_f32_16x16x32_bf16(v0, pb1, ot[0][1], 0, 0, 0);
            ot[1][1] = __builtin_amdgcn_mfma_f32_16x16x32_bf16(v1, pb1, ot[1][1], 0, 0, 0);
            osum0 = __builtin_amdgcn_mfma_f32_16x16x32_bf16(ones, pb0, osum0, 0, 0, 0);
            osum1 = __builtin_amdgcn_mfma_f32_16x16x32_bf16(ones, pb1, osum1, 0, 0, 0);
        }
    }

    // ---- every lane holds the full 2048-key rowsum for its q = l16
    const float inv0 = 1.0f / osum0[0], inv1 = 1.0f / osum1[0];

    #pragma unroll
    for (int qh = 0; qh < 2; ++qh) {
        const float inv = qh ? inv1 : inv0;
        #pragma unroll
        for (int dhh = 0; dhh < 2; ++dhh) {
            f32x4 w;
            #pragma unroll
            for (int r = 0; r < 4; ++r) w[r] = ot[dhh][qh][r] * inv;
            *(f32x4*)(out + ((size_t)b*N_ + qrow0 + qh*16 + l16)*D_
                          + h*DH_ + dhh*16 + q4*4) = w;
        }
    }
}

// ---------------------------------------------------------------------------
extern "C" void kernel_launch(void* const* d_in, const int* in_sizes, int n_in,
                              void* d_out, int out_size, void* d_ws, size_t ws_size,
                              hipStream_t stream)
{
    const float* x  = (const float*)d_in[0];
    const float* Wq = (const float*)d_in[1];
    const float* bq = (const float*)d_in[2];
    const float* Wk = (const float*)d_in[3];
    const float* bk = (const float*)d_in[4];
    const float* Wv = (const float*)d_in[5];
    const float* bv = (const float*)d_in[6];
    float* out = (float*)d_out;

    bf16* Qg = (bf16*)d_ws;
    bf16* Kg = Qg + QKV_ELEMS;
    bf16* Vg = Kg + QKV_ELEMS;

    qkv_proj_kernel<<<dim3(B_*H_*32), dim3(256), 0, stream>>>(
        x, Wq, bq, Wk, bk, Wv, bv, Qg, Kg, Vg);
    attn_kernel<<<dim3(B_*H_*(N_/128)), dim3(256), 0, stream>>>(Qg, Kg, Vg, out);
}